// Round 12
// baseline (96.301 us; speedup 1.0000x reference)
//
#include <hip/hip_runtime.h>
#include <hip/hip_bf16.h>

#define BATCH 8192
#define DIN   4096
#define H1    128
#define NLAT  512
#define LAT   32
#define BM    16
#define PP    130           // pacc pitch (ushorts)

typedef short bf16x8 __attribute__((ext_vector_type(8)));
typedef short bf16x4 __attribute__((ext_vector_type(4)));
typedef float f32x4  __attribute__((ext_vector_type(4)));

static __device__ __forceinline__ unsigned short f2bf(float f) {
  union { float f; unsigned u; } v; v.f = f;
  return (unsigned short)((v.u + 0x7FFFu + ((v.u >> 16) & 1u)) >> 16);  // RNE
}
static __device__ __forceinline__ float bf2f(unsigned short u) {
  union { unsigned u; float f; } v; v.u = ((unsigned)u) << 16; return v.f;
}

// ---- prep_all: W1 -> W1B frag-packed bf16; W2 -> W2B frag-packed bf16;
// decoders -> decT [32][4096] f32. (unchanged, verified R4-R11) ----
__global__ void prep_all(const float* __restrict__ W1, const float* __restrict__ W2,
                         const float* __restrict__ dec,
                         unsigned short* __restrict__ W1B,
                         unsigned short* __restrict__ W2B,
                         float* __restrict__ decT) {
  int b = blockIdx.x;
  int t = threadIdx.x;
  if (b < 256) {
    int gi = (b << 2) + (t >> 6);
    int lane = t & 63;
    int kb = ((gi >> 3) << 5) + ((lane >> 4) << 3);
    int c = ((gi & 7) << 4) + (lane & 15);
    union { bf16x8 v; unsigned short u[8]; } o;
#pragma unroll
    for (int j = 0; j < 8; j++) o.u[j] = f2bf(W1[(size_t)(kb + j) * H1 + c]);
    *(bf16x8*)(W1B + (((size_t)gi << 6) + lane) * 8) = o.v;
  } else if (b < 288) {
    int gi = ((b - 256) << 2) + (t >> 6);
    int lane = t & 63;
    int kb = ((gi >> 5) << 5) + ((lane >> 4) << 3);
    int c = ((gi & 31) << 4) + (lane & 15);
    union { bf16x8 v; unsigned short u[8]; } o;
#pragma unroll
    for (int j = 0; j < 8; j++) o.u[j] = f2bf(W2[(size_t)(kb + j) * NLAT + c]);
    *(bf16x8*)(W2B + (((size_t)gi << 6) + lane) * 8) = o.v;
  } else {
    __shared__ float tbuf[32][33];
    int d0 = (b - 288) * 32;
    int tx = t & 31, ty = t >> 5;
#pragma unroll
    for (int i = 0; i < 32; i += 8)
      tbuf[ty + i][tx] = dec[(size_t)(d0 + ty + i) * LAT + tx];
    __syncthreads();
#pragma unroll
    for (int i = 0; i < 32; i += 8)
      decT[(size_t)(ty + i) * DIN + (d0 + tx)] = tbuf[tx][ty + i];
  }
}

// ---- enc_kernel: h = relu(x@W1+b1); z = h@W2+b2 -> zout; zsum -> zsumg.
// REG-DIRECT A: phase A uses NO LDS and NO barriers. Lane (fr,g) loads its
// MFMA A-fragment x[rbase+fr][k0+g*8..+8] straight from global (wave = 16
// full 128B lines per chunk-pair, k-order matches W1B packing), converts
// f32->bf16 in-reg, MFMAs against 8 B-frags. 16 independent chunks/wave ->
// compiler pipelines freely; no lgkmcnt/vmcnt program-order chains.
// 8 waves x wave-private K=512. Phase B/epilogue identical to R11. ----
__global__ __launch_bounds__(512, 2) void enc_kernel(
    const float* __restrict__ x, const unsigned short* __restrict__ W1B,
    const unsigned short* __restrict__ W2B,
    const float* __restrict__ b1, const float* __restrict__ b2,
    float* __restrict__ zout, float* __restrict__ zsumg) {
  __shared__ unsigned short pacc[8 * BM * PP];   // 33.3 KB bf16 partials
  __shared__ unsigned short hs[16 * 128];        // 4 KB, XOR-swizzled
  __shared__ float zsp[8 * BM * 33];             // 16.9 KB

  const int t = threadIdx.x;
  const int rbase = blockIdx.x << 4;
  const int w = t >> 6, lane = t & 63;
  const int g = lane >> 4, fr = lane & 15;

  // ---- phase A: reg-direct, barrier-free. Wave w: K in [w*512, +512). ----
  f32x4 acc[8];
#pragma unroll
  for (int i = 0; i < 8; i++) acc[i] = (f32x4){0.f, 0.f, 0.f, 0.f};

  const float* arow = x + (size_t)(rbase + fr) * DIN + (w << 9) + (g << 3);
#pragma unroll 4
  for (int c = 0; c < 16; ++c) {
    f32x4 a0 = *(const f32x4*)(arow + (c << 5));
    f32x4 a1 = *(const f32x4*)(arow + (c << 5) + 4);
    union { bf16x8 v; unsigned short u[8]; } af;
#pragma unroll
    for (int j = 0; j < 4; j++) { af.u[j] = f2bf(a0[j]); af.u[4 + j] = f2bf(a1[j]); }
    const unsigned short* bp =
        W1B + (((size_t)((w << 4) + c) << 3) << 9) + (lane << 3);
#pragma unroll
    for (int cf = 0; cf < 8; ++cf) {
      bf16x8 bv = *(const bf16x8*)(bp + ((size_t)cf << 9));
      acc[cf] = __builtin_amdgcn_mfma_f32_16x16x32_bf16(af.v, bv, acc[cf], 0, 0, 0);
    }
  }

  // partial acc -> pacc bf16. C/D: col=fr, row=g*4+j.
#pragma unroll
  for (int cf = 0; cf < 8; ++cf)
#pragma unroll
    for (int j = 0; j < 4; ++j)
      pacc[(w * BM + (g << 2) + j) * PP + (cf << 4) + fr] = f2bf(acc[cf][j]);
  __syncthreads();

  // reduce 8 partials + b1 + relu -> hs (bf16, XOR-swizzled 8-granules).
  {
    const int r = t >> 5, c4 = (t & 31) << 2;
    float s0 = b1[c4], s1 = b1[c4 + 1], s2 = b1[c4 + 2], s3 = b1[c4 + 3];
#pragma unroll
    for (int wv = 0; wv < 8; ++wv) {
      union { bf16x4 v; unsigned short u[4]; } p;
      p.v = *(const bf16x4*)&pacc[(wv * BM + r) * PP + c4];
      s0 += bf2f(p.u[0]); s1 += bf2f(p.u[1]); s2 += bf2f(p.u[2]); s3 += bf2f(p.u[3]);
    }
    union { bf16x4 v; unsigned short u[4]; } o;
    o.u[0] = f2bf(fmaxf(s0, 0.f)); o.u[1] = f2bf(fmaxf(s1, 0.f));
    o.u[2] = f2bf(fmaxf(s2, 0.f)); o.u[3] = f2bf(fmaxf(s3, 0.f));
    const int gi = c4 >> 3;
    *(bf16x4*)(hs + (r << 7) + ((gi ^ (r & 15)) << 3) + (c4 & 7)) = o.v;
  }
  __syncthreads();

  // ---- phase B: z = h @ W2 + b2. Wave w: 16 rows x cols w*64..+64. ----
  f32x4 acc2[4];
#pragma unroll
  for (int i = 0; i < 4; i++) acc2[i] = (f32x4){0.f, 0.f, 0.f, 0.f};
#pragma unroll
  for (int k32 = 0; k32 < 4; ++k32) {
    bf16x8 a0 = *(const bf16x8*)(hs + (fr << 7) +
                  ((((k32 << 2) + g) ^ (fr & 15)) << 3));
#pragma unroll
    for (int cc = 0; cc < 4; ++cc) {
      bf16x8 bv = *(const bf16x8*)(W2B +
          (((size_t)((k32 << 5) + (w << 2) + cc)) << 9) + (lane << 3));
      acc2[cc] = __builtin_amdgcn_mfma_f32_16x16x32_bf16(a0, bv, acc2[cc], 0, 0, 0);
    }
  }
  // z write + zsum fold. col = w*64+cc*16+fr; latent = (cc&1)*16+fr.
  {
    f32x4 zv[4];
#pragma unroll
    for (int cc = 0; cc < 4; ++cc) {
      const float b2v = b2[(w << 6) + (cc << 4) + fr];
#pragma unroll
      for (int j = 0; j < 4; j++) zv[cc][j] = acc2[cc][j] + b2v;
    }
    const int row0 = g << 2;
#pragma unroll
    for (int j = 0; j < 4; j++) {
#pragma unroll
      for (int cc = 0; cc < 4; ++cc)
        zout[(size_t)(rbase + row0 + j) * NLAT + (w << 6) + (cc << 4) + fr] = zv[cc][j];
      zsp[(w * BM + row0 + j) * 33 + fr]      = zv[0][j] + zv[2][j];
      zsp[(w * BM + row0 + j) * 33 + 16 + fr] = zv[1][j] + zv[3][j];
    }
  }
  __syncthreads();
  // reduce 8 wave-partials -> zsumg (512 thr = 16x32 exactly)
  {
    const int r = t >> 5, l = t & 31;
    float s = 0.f;
#pragma unroll
    for (int wv = 0; wv < 8; ++wv) s += zsp[(wv * BM + r) * 33 + l];
    zsumg[(size_t)(rbase + r) * LAT + l] = s;
  }
}

// ---- recon_kernel: rout[b][d] = sum_l zsum[b][l] * decT[l][d]. (unchanged) ----
__global__ __launch_bounds__(256) void recon_kernel(
    const float* __restrict__ zsumg, const float* __restrict__ decT,
    float* __restrict__ rout) {
  __shared__ float zs[32][32];
  int t = threadIdx.x;
  int rbase = (blockIdx.x >> 4) << 5;
  int dcol0 = (blockIdx.x & 15) << 8;
  {
    int r = t >> 3, c4 = (t & 7) << 2;
    *(f32x4*)&zs[r][c4] = *(const f32x4*)(zsumg + (size_t)(rbase + r) * LAT + c4);
  }
  __syncthreads();
  int wq = t >> 6, lane = t & 63;
  int r0 = wq << 3;
  int dcol = dcol0 + (lane << 2);
  f32x4 acc[8];
#pragma unroll
  for (int r = 0; r < 8; r++) acc[r] = (f32x4){0.f, 0.f, 0.f, 0.f};
#pragma unroll 4
  for (int l = 0; l < 32; l++) {
    f32x4 dv = *(const f32x4*)(decT + (size_t)l * DIN + dcol);
#pragma unroll
    for (int r = 0; r < 8; r++) {
      float zv = zs[r0 + r][l];
#pragma unroll
      for (int j = 0; j < 4; j++) acc[r][j] += zv * dv[j];
    }
  }
#pragma unroll
  for (int r = 0; r < 8; r++)
    *(f32x4*)(rout + (size_t)(rbase + r0 + r) * DIN + dcol) = acc[r];
}

extern "C" void kernel_launch(void* const* d_in, const int* in_sizes, int n_in,
                              void* d_out, int out_size, void* d_ws, size_t ws_size,
                              hipStream_t stream) {
  const float* x   = (const float*)d_in[0];
  const float* W1  = (const float*)d_in[1];
  const float* b1  = (const float*)d_in[2];
  const float* W2  = (const float*)d_in[3];
  const float* b2  = (const float*)d_in[4];
  const float* dec = (const float*)d_in[5];
  float* zout = (float*)d_out;
  float* rout = zout + (size_t)BATCH * NLAT;

  char* ws = (char*)d_ws;
  unsigned short* W1B = (unsigned short*)ws;                          // 1 MB
  unsigned short* W2B = (unsigned short*)(ws + (1u << 20));           // 128 KB
  float* decT  = (float*)(ws + (1u << 20) + (1u << 17));              // 512 KB
  float* zsumg = (float*)(ws + (1u << 20) + (1u << 17) + (1u << 19)); // 1 MB

  prep_all<<<dim3(416), 256, 0, stream>>>(W1, W2, dec, W1B, W2B, decT);
  enc_kernel<<<dim3(BATCH / BM), 512, 0, stream>>>(x, W1B, W2B, b1, b2, zout, zsumg);
  recon_kernel<<<dim3(4096), 256, 0, stream>>>(zsumg, decT, rout);
}